// Round 4
// baseline (391.964 us; speedup 1.0000x reference)
//
#include <hip/hip_runtime.h>
#include <hip/hip_bf16.h>

typedef __attribute__((ext_vector_type(8))) short short8;
typedef __attribute__((ext_vector_type(4))) short short4v;
typedef __attribute__((ext_vector_type(4))) float float4v;

#define NB 8
#define NH 12
#define NN 1024
#define ND 64
#define NC 768

__device__ __forceinline__ short f2bf(float f) {
  __hip_bfloat16 h = __float2bfloat16(f);
  union { __hip_bfloat16 h; short s; } u; u.h = h; return u.s;
}
__device__ __forceinline__ unsigned pk2(float a, float b) {
  unsigned ua = (unsigned short)f2bf(a);
  unsigned ub = (unsigned short)f2bf(b);
  return ua | (ub << 16);
}

// ---------------- GEMM: MODE 0 = QKV (A fp32, scatter to Q/K bf16 + V^T),
// ----------------       MODE 1 = proj (A bf16, +bias, fp32 out) ----------------
template<int MODE>
__global__ __launch_bounds__(256, 2)
void gemm_kernel(const void* __restrict__ Ap, const float* __restrict__ Bw,
                 const float* __restrict__ bias,
                 __hip_bfloat16* __restrict__ Qo, __hip_bfloat16* __restrict__ Ko,
                 __hip_bfloat16* __restrict__ VTo, float* __restrict__ Out)
{
  __shared__ short As[128 * 40];
  __shared__ short Bs[128 * 40];
  const int tid = threadIdx.x;
  const int w = tid >> 6, lane = tid & 63, lr = lane & 15, lg = lane >> 4;
  const int wr = w >> 1, wc = w & 1;
  const int n0 = blockIdx.x * 128, m0 = blockIdx.y * 128;

  float4v acc[4][4];
  #pragma unroll
  for (int i = 0; i < 4; i++)
    #pragma unroll
    for (int j = 0; j < 4; j++)
      acc[i][j] = (float4v){0.f, 0.f, 0.f, 0.f};

  for (int kt = 0; kt < 768; kt += 32) {
    if (MODE == 0) {
      const float* A = (const float*)Ap;
      #pragma unroll
      for (int i2 = 0; i2 < 4; i2++) {
        int c = tid + 256 * i2;
        int row = c >> 3, c4 = c & 7;
        float4v v = *(const float4v*)(A + (size_t)(m0 + row) * 768 + kt + c4 * 4);
        short4v s = { f2bf(v[0]), f2bf(v[1]), f2bf(v[2]), f2bf(v[3]) };
        *(short4v*)(&As[row * 40 + c4 * 4]) = s;
      }
    } else {
      const __hip_bfloat16* A = (const __hip_bfloat16*)Ap;
      #pragma unroll
      for (int i2 = 0; i2 < 2; i2++) {
        int c = tid + 256 * i2;
        int row = c >> 2, c8 = c & 3;
        *(short8*)(&As[row * 40 + c8 * 8]) =
            *(const short8*)(A + (size_t)(m0 + row) * 768 + kt + c8 * 8);
      }
    }
    #pragma unroll
    for (int i2 = 0; i2 < 4; i2++) {
      int c = tid + 256 * i2;
      int row = c >> 3, c4 = c & 7;
      float4v v = *(const float4v*)(Bw + (size_t)(n0 + row) * 768 + kt + c4 * 4);
      short4v s = { f2bf(v[0]), f2bf(v[1]), f2bf(v[2]), f2bf(v[3]) };
      *(short4v*)(&Bs[row * 40 + c4 * 4]) = s;
    }
    __syncthreads();

    short8 af[4], bfr[4];
    #pragma unroll
    for (int i = 0; i < 4; i++)
      af[i] = *(const short8*)(&As[(wr * 64 + i * 16 + lr) * 40 + lg * 8]);
    #pragma unroll
    for (int j = 0; j < 4; j++)
      bfr[j] = *(const short8*)(&Bs[(wc * 64 + j * 16 + lr) * 40 + lg * 8]);
    #pragma unroll
    for (int i = 0; i < 4; i++)
      #pragma unroll
      for (int j = 0; j < 4; j++)
        acc[i][j] = __builtin_amdgcn_mfma_f32_16x16x32_bf16(af[i], bfr[j], acc[i][j], 0, 0, 0);
    __syncthreads();
  }

  #pragma unroll
  for (int i = 0; i < 4; i++) {
    #pragma unroll
    for (int j = 0; j < 4; j++) {
      #pragma unroll
      for (int r = 0; r < 4; r++) {
        float val = acc[i][j][r];
        int mg_ = m0 + wr * 64 + i * 16 + lg * 4 + r;
        int ng_ = n0 + wc * 64 + j * 16 + lr;
        if (MODE == 0) {
          int s = ng_ / 768;
          int rem = ng_ - s * 768;
          int h = rem >> 6, d = rem & 63;
          int b = mg_ >> 10, n = mg_ & 1023;
          if (s == 0)
            Qo[(((size_t)b * NH + h) * NN + n) * ND + d] = __float2bfloat16(val * 0.125f);
          else if (s == 1)
            Ko[(((size_t)b * NH + h) * NN + n) * ND + d] = __float2bfloat16(val);
          else  // V stored transposed: VT[b][h][d][m]
            VTo[(((size_t)b * NH + h) * ND + d) * NN + n] = __float2bfloat16(val);
        } else {
          Out[(size_t)mg_ * NC + ng_] = val + bias[ng_];
        }
      }
    }
  }
}

// ---------------- fused talking-heads attention, MFMA mixes, prefetched ----------------
// grid = 512 blocks, 256 threads (4 waves). b = blockIdx&7 -> XCD-local K/VT working set.
__global__ __launch_bounds__(256, 2)
void attn_kernel(const __hip_bfloat16* __restrict__ Qg, const __hip_bfloat16* __restrict__ Kg,
                 const __hip_bfloat16* __restrict__ VTg,
                 const float* __restrict__ convl, const float* __restrict__ convw,
                 __hip_bfloat16* __restrict__ AOut)
{
  __shared__ short Sb[32 * 576];   // [chunk(32)][col(16)][k(36)] bf16
  __shared__ short pm[16 * 648];   // [o2(16)][n(16)][m(40)] bf16
  __shared__ short lwA[512];       // lw A-frag [o(16)][h(32)], zero-padded
  __shared__ short wwT[512];       // ww B-frag [o(16? k)][o2(32)], zero-padded

  const int tid = threadIdx.x;
  const int w = tid >> 6, lane = tid & 63, lr = lane & 15, lg = lane >> 4;
  const int b = blockIdx.x & 7;          // XCD swizzle: all blocks of batch b on one XCD
  const int n0 = (blockIdx.x >> 3) * 16;
  const float4v zf = (float4v){0.f, 0.f, 0.f, 0.f};

  for (int i = tid; i < 512; i += 256) {
    int r = i >> 5, k = i & 31;
    bool v = (r < 12) && (k < 12);
    lwA[i] = v ? f2bf(convl[r * 12 + k]) : (short)0;
    wwT[i] = v ? f2bf(convw[r * 12 + k]) : (short)0;
  }
  for (int i = tid; i < 512; i += 256) {   // zero Sb k-pad [12..35]
    short* p = &Sb[i * 36 + 12];
    #pragma unroll
    for (int j = 0; j < 24; j++) p[j] = 0;
  }

  // Q A-fragments: wave w owns heads 3w..3w+2
  short8 qf[3][2];
  #pragma unroll
  for (int hh = 0; hh < 3; hh++)
    #pragma unroll
    for (int ks = 0; ks < 2; ks++)
      qf[hh][ks] = *(const short8*)(Qg +
          (((size_t)b * NH + w * 3 + hh) * NN + n0 + lr) * ND + ks * 32 + lg * 8);

  // K B-frag prefetch registers (12 x short8 = 48 VGPR)
  short8 kreg[3][2][2];
  auto loadK = [&](int t) {
    const int m0t = t * 32;
    #pragma unroll
    for (int hh = 0; hh < 3; hh++) {
      const size_t kbase = (((size_t)b * NH + w * 3 + hh) * NN + m0t) * ND;
      #pragma unroll
      for (int j = 0; j < 2; j++)
        #pragma unroll
        for (int ks = 0; ks < 2; ks++)
          kreg[hh][j][ks] = *(const short8*)(Kg + kbase +
              (size_t)(j * 16 + lr) * ND + ks * 32 + lg * 8);
    }
  };
  loadK(0);
  __syncthreads();
  const short8 lwf = *(const short8*)(&lwA[lr * 32 + lg * 8]);  // A[row=o][k=h]
  const short8 wwf = *(const short8*)(&wwT[lr * 32 + lg * 8]);  // B[k=o][col=o2]

  // ================= PASS 1: L[o][n] = sum_m exp(S') =================
  float Lacc[4][4];
  #pragma unroll
  for (int r = 0; r < 4; r++)
    #pragma unroll
    for (int nn = 0; nn < 4; nn++) Lacc[r][nn] = 0.f;

  for (int t = 0; t < 32; t++) {
    #pragma unroll
    for (int hh = 0; hh < 3; hh++) {
      const int h = w * 3 + hh;
      #pragma unroll
      for (int j = 0; j < 2; j++) {
        float4v a = zf;
        #pragma unroll
        for (int ks = 0; ks < 2; ks++)
          a = __builtin_amdgcn_mfma_f32_16x16x32_bf16(qf[hh][ks], kreg[hh][j][ks], a, 0, 0, 0);
        #pragma unroll
        for (int r = 0; r < 4; r++)
          Sb[((lg * 4 + r) * 2 + j) * 576 + lr * 36 + h] = f2bf(a[r]);
      }
    }
    loadK(t < 31 ? t + 1 : 0);   // last iter preloads pass-2 t=0
    __syncthreads();
    #pragma unroll
    for (int cc = 0; cc < 8; cc++) {
      const int c = w * 8 + cc;
      short8 sb = *(const short8*)(&Sb[c * 576 + lr * 36 + lg * 8]);
      float4v d = __builtin_amdgcn_mfma_f32_16x16x32_bf16(lwf, sb, zf, 0, 0, 0);
      #pragma unroll
      for (int r = 0; r < 4; r++)
        Lacc[r][cc >> 1] += __expf(d[r]);
    }
    __syncthreads();
  }
  float logLreg[4][4];
  #pragma unroll
  for (int r = 0; r < 4; r++)
    #pragma unroll
    for (int nn = 0; nn < 4; nn++) {
      float v = Lacc[r][nn];
      v += __shfl_xor(v, 1);
      v += __shfl_xor(v, 2);
      v += __shfl_xor(v, 4);
      v += __shfl_xor(v, 8);
      logLreg[r][nn] = __logf(v);
    }

  // ================= PASS 2: P=exp(S'-logL) -> conv_w -> PV =================
  float4v oacc[3][4];
  #pragma unroll
  for (int hh = 0; hh < 3; hh++)
    #pragma unroll
    for (int jd = 0; jd < 4; jd++) oacc[hh][jd] = zf;

  for (int t = 0; t <= 32; t++) {
    // ---- Phase A: [VT(t-1) issue] QK(t)->Sb [K(t+1) issue] PV(t-1) ----
    short8 vt0[3][2];
    if (t > 0) {
      const int m0v = (t - 1) * 32;
      #pragma unroll
      for (int hh = 0; hh < 3; hh++) {
        const size_t vbase = ((size_t)b * NH + w * 3 + hh) * ND * NN;
        #pragma unroll
        for (int jj = 0; jj < 2; jj++)
          vt0[hh][jj] = *(const short8*)(VTg + vbase +
              (size_t)(jj * 16 + lr) * NN + m0v + lg * 8);
      }
    }
    if (t < 32) {
      #pragma unroll
      for (int hh = 0; hh < 3; hh++) {
        const int h = w * 3 + hh;
        #pragma unroll
        for (int j = 0; j < 2; j++) {
          float4v a = zf;
          #pragma unroll
          for (int ks = 0; ks < 2; ks++)
            a = __builtin_amdgcn_mfma_f32_16x16x32_bf16(qf[hh][ks], kreg[hh][j][ks], a, 0, 0, 0);
          #pragma unroll
          for (int r = 0; r < 4; r++)
            Sb[((lg * 4 + r) * 2 + j) * 576 + lr * 36 + h] = f2bf(a[r]);
        }
      }
      if (t < 31) loadK(t + 1);
    }
    if (t > 0) {
      const int m0v = (t - 1) * 32;
      short8 pf[3];
      #pragma unroll
      for (int hh = 0; hh < 3; hh++)
        pf[hh] = *(const short8*)(&pm[(w * 3 + hh) * 648 + lr * 40 + lg * 8]);
      #pragma unroll
      for (int hh = 0; hh < 3; hh++)
        #pragma unroll
        for (int jj = 0; jj < 2; jj++)
          oacc[hh][jj] = __builtin_amdgcn_mfma_f32_16x16x32_bf16(vt0[hh][jj], pf[hh], oacc[hh][jj], 0, 0, 0);
      short8 vt1[3][2];
      #pragma unroll
      for (int hh = 0; hh < 3; hh++) {
        const size_t vbase = ((size_t)b * NH + w * 3 + hh) * ND * NN;
        #pragma unroll
        for (int jj = 0; jj < 2; jj++)
          vt1[hh][jj] = *(const short8*)(VTg + vbase +
              (size_t)((2 + jj) * 16 + lr) * NN + m0v + lg * 8);
      }
      #pragma unroll
      for (int hh = 0; hh < 3; hh++)
        #pragma unroll
        for (int jj = 0; jj < 2; jj++)
          oacc[hh][2 + jj] = __builtin_amdgcn_mfma_f32_16x16x32_bf16(vt1[hh][jj], pf[hh], oacc[hh][2 + jj], 0, 0, 0);
    }
    __syncthreads();
    // ---- Phase B: conv_l -> exp -> conv_w -> pm ----
    if (t < 32) {
      #pragma unroll
      for (int cc = 0; cc < 8; cc++) {
        const int c = w * 8 + cc;
        short8 sb = *(const short8*)(&Sb[c * 576 + lr * 36 + lg * 8]);
        float4v d = __builtin_amdgcn_mfma_f32_16x16x32_bf16(lwf, sb, zf, 0, 0, 0);
        float p0 = __expf(d[0] - logLreg[0][cc >> 1]);
        float p1 = __expf(d[1] - logLreg[1][cc >> 1]);
        float p2 = __expf(d[2] - logLreg[2][cc >> 1]);
        float p3 = __expf(d[3] - logLreg[3][cc >> 1]);
        unsigned* dst = (unsigned*)(&Sb[c * 576 + lr * 36 + lg * 4]);
        dst[0] = pk2(p0, p1);
        dst[1] = pk2(p2, p3);
      }
      asm volatile("s_waitcnt lgkmcnt(0)" ::: "memory");
      __builtin_amdgcn_sched_barrier(0);
      #pragma unroll
      for (int cc = 0; cc < 8; cc++) {
        const int c = w * 8 + cc;
        short8 pb = *(const short8*)(&Sb[c * 576 + lr * 36 + lg * 8]);
        float4v d = __builtin_amdgcn_mfma_f32_16x16x32_bf16(pb, wwf, zf, 0, 0, 0);
        unsigned* dst = (unsigned*)(&pm[lr * 648 + (c >> 1) * 40 + (c & 1) * 16 + lg * 4]);
        dst[0] = pk2(d[0], d[1]);
        dst[1] = pk2(d[2], d[3]);
      }
    }
    __syncthreads();
  }

  // epilogue: lane holds (o2, d = jd*16+lg*4.., n = n0+lr)
  #pragma unroll
  for (int hh = 0; hh < 3; hh++) {
    const int o2 = w * 3 + hh;
    #pragma unroll
    for (int jd = 0; jd < 4; jd++) {
      size_t base = ((size_t)b * NN + n0 + lr) * NC + o2 * 64 + jd * 16 + lg * 4;
      unsigned* dst = (unsigned*)(&AOut[base]);
      dst[0] = pk2(oacc[hh][jd][0], oacc[hh][jd][1]);
      dst[1] = pk2(oacc[hh][jd][2], oacc[hh][jd][3]);
    }
  }
}

extern "C" void kernel_launch(void* const* d_in, const int* in_sizes, int n_in,
                              void* d_out, int out_size, void* d_ws, size_t ws_size,
                              hipStream_t stream) {
  const float* x      = (const float*)d_in[0];
  const float* w_qkv  = (const float*)d_in[1];
  const float* w_proj = (const float*)d_in[2];
  const float* b_proj = (const float*)d_in[3];
  const float* conv_l = (const float*)d_in[4];
  const float* conv_w = (const float*)d_in[5];
  float* out = (float*)d_out;

  const size_t NE = (size_t)NB * NH * NN * ND;
  __hip_bfloat16* Qb = (__hip_bfloat16*)d_ws;
  __hip_bfloat16* Kb = Qb + NE;
  __hip_bfloat16* VT = Kb + NE;
  __hip_bfloat16* AO = VT + NE;   // [B*N][C] bf16

  gemm_kernel<0><<<dim3(18, 64), 256, 0, stream>>>(x, w_qkv, nullptr, Qb, Kb, VT, nullptr);
  attn_kernel<<<dim3(512), 256, 0, stream>>>(Qb, Kb, VT, conv_l, conv_w, AO);
  gemm_kernel<1><<<dim3(6, 64), 256, 0, stream>>>(AO, w_proj, b_proj, nullptr, nullptr, nullptr, out);
}

// Round 5
// 375.456 us; speedup vs baseline: 1.0440x; 1.0440x over previous
//
#include <hip/hip_runtime.h>
#include <hip/hip_bf16.h>

typedef __attribute__((ext_vector_type(8))) short short8;
typedef __attribute__((ext_vector_type(4))) short short4v;
typedef __attribute__((ext_vector_type(4))) float float4v;

#define NB 8
#define NH 12
#define NN 1024
#define ND 64
#define NC 768

#define RAWBAR() do { \
  asm volatile("s_waitcnt lgkmcnt(0)" ::: "memory"); \
  __builtin_amdgcn_s_barrier(); \
} while (0)

__device__ __forceinline__ short f2bf(float f) {
  __hip_bfloat16 h = __float2bfloat16(f);
  union { __hip_bfloat16 h; short s; } u; u.h = h; return u.s;
}
__device__ __forceinline__ unsigned pk2(float a, float b) {
  unsigned ua = (unsigned short)f2bf(a);
  unsigned ub = (unsigned short)f2bf(b);
  return ua | (ub << 16);
}

// ---------------- GEMM: MODE 0 = QKV (A fp32, scatter to Q/K bf16 + V^T),
// ----------------       MODE 1 = proj (A bf16, +bias, fp32 out) ----------------
template<int MODE>
__global__ __launch_bounds__(256, 2)
void gemm_kernel(const void* __restrict__ Ap, const float* __restrict__ Bw,
                 const float* __restrict__ bias,
                 __hip_bfloat16* __restrict__ Qo, __hip_bfloat16* __restrict__ Ko,
                 __hip_bfloat16* __restrict__ VTo, float* __restrict__ Out)
{
  __shared__ short As[128 * 40];
  __shared__ short Bs[128 * 40];
  const int tid = threadIdx.x;
  const int w = tid >> 6, lane = tid & 63, lr = lane & 15, lg = lane >> 4;
  const int wr = w >> 1, wc = w & 1;
  const int n0 = blockIdx.x * 128, m0 = blockIdx.y * 128;

  float4v acc[4][4];
  #pragma unroll
  for (int i = 0; i < 4; i++)
    #pragma unroll
    for (int j = 0; j < 4; j++)
      acc[i][j] = (float4v){0.f, 0.f, 0.f, 0.f};

  for (int kt = 0; kt < 768; kt += 32) {
    if (MODE == 0) {
      const float* A = (const float*)Ap;
      #pragma unroll
      for (int i2 = 0; i2 < 4; i2++) {
        int c = tid + 256 * i2;
        int row = c >> 3, c4 = c & 7;
        float4v v = *(const float4v*)(A + (size_t)(m0 + row) * 768 + kt + c4 * 4);
        short4v s = { f2bf(v[0]), f2bf(v[1]), f2bf(v[2]), f2bf(v[3]) };
        *(short4v*)(&As[row * 40 + c4 * 4]) = s;
      }
    } else {
      const __hip_bfloat16* A = (const __hip_bfloat16*)Ap;
      #pragma unroll
      for (int i2 = 0; i2 < 2; i2++) {
        int c = tid + 256 * i2;
        int row = c >> 2, c8 = c & 3;
        *(short8*)(&As[row * 40 + c8 * 8]) =
            *(const short8*)(A + (size_t)(m0 + row) * 768 + kt + c8 * 8);
      }
    }
    #pragma unroll
    for (int i2 = 0; i2 < 4; i2++) {
      int c = tid + 256 * i2;
      int row = c >> 3, c4 = c & 7;
      float4v v = *(const float4v*)(Bw + (size_t)(n0 + row) * 768 + kt + c4 * 4);
      short4v s = { f2bf(v[0]), f2bf(v[1]), f2bf(v[2]), f2bf(v[3]) };
      *(short4v*)(&Bs[row * 40 + c4 * 4]) = s;
    }
    __syncthreads();

    short8 af[4], bfr[4];
    #pragma unroll
    for (int i = 0; i < 4; i++)
      af[i] = *(const short8*)(&As[(wr * 64 + i * 16 + lr) * 40 + lg * 8]);
    #pragma unroll
    for (int j = 0; j < 4; j++)
      bfr[j] = *(const short8*)(&Bs[(wc * 64 + j * 16 + lr) * 40 + lg * 8]);
    #pragma unroll
    for (int i = 0; i < 4; i++)
      #pragma unroll
      for (int j = 0; j < 4; j++)
        acc[i][j] = __builtin_amdgcn_mfma_f32_16x16x32_bf16(af[i], bfr[j], acc[i][j], 0, 0, 0);
    __syncthreads();
  }

  #pragma unroll
  for (int i = 0; i < 4; i++) {
    #pragma unroll
    for (int j = 0; j < 4; j++) {
      #pragma unroll
      for (int r = 0; r < 4; r++) {
        float val = acc[i][j][r];
        int mg_ = m0 + wr * 64 + i * 16 + lg * 4 + r;
        int ng_ = n0 + wc * 64 + j * 16 + lr;
        if (MODE == 0) {
          int s = ng_ / 768;
          int rem = ng_ - s * 768;
          int h = rem >> 6, d = rem & 63;
          int b = mg_ >> 10, n = mg_ & 1023;
          if (s == 0)
            Qo[(((size_t)b * NH + h) * NN + n) * ND + d] = __float2bfloat16(val * 0.125f);
          else if (s == 1)
            Ko[(((size_t)b * NH + h) * NN + n) * ND + d] = __float2bfloat16(val);
          else  // V stored transposed: VT[b][h][d][m]
            VTo[(((size_t)b * NH + h) * ND + d) * NN + n] = __float2bfloat16(val);
        } else {
          Out[(size_t)mg_ * NC + ng_] = val + bias[ng_];
        }
      }
    }
  }
}

// ---------------- fused talking-heads attention ----------------
// grid = 512 blocks, 256 threads (4 waves). b = blockIdx&7 -> XCD-local K/VT.
// Raw s_barrier + lgkmcnt-only waits: global prefetches stay in flight across barriers.
__global__ __launch_bounds__(256, 2)
void attn_kernel(const __hip_bfloat16* __restrict__ Qg, const __hip_bfloat16* __restrict__ Kg,
                 const __hip_bfloat16* __restrict__ VTg,
                 const float* __restrict__ convl, const float* __restrict__ convw,
                 __hip_bfloat16* __restrict__ AOut)
{
  __shared__ short Sb[32 * 576];   // [chunk(32)][col(16)][k(36)] bf16
  __shared__ short pm[16 * 648];   // [o2(16)][n(16)][m(40)] bf16
  __shared__ short lwA[512];       // lw A-frag [o(16)][h(32)], zero-padded
  __shared__ short wwT[512];       // ww B-frag [k=o(16)][o2(32)], zero-padded

  const int tid = threadIdx.x;
  const int w = tid >> 6, lane = tid & 63, lr = lane & 15, lg = lane >> 4;
  const int b = blockIdx.x & 7;          // XCD swizzle
  const int n0 = (blockIdx.x >> 3) * 16;
  const float4v zf = (float4v){0.f, 0.f, 0.f, 0.f};

  for (int i = tid; i < 512; i += 256) {
    int r = i >> 5, k = i & 31;
    bool v = (r < 12) && (k < 12);
    lwA[i] = v ? f2bf(convl[r * 12 + k]) : (short)0;
    wwT[i] = v ? f2bf(convw[r * 12 + k]) : (short)0;
  }
  for (int i = tid; i < 512; i += 256) {   // zero Sb k-pad [12..35]
    short* p = &Sb[i * 36 + 12];
    #pragma unroll
    for (int j = 0; j < 24; j++) p[j] = 0;
  }

  // Q A-fragments: wave w owns heads 3w..3w+2
  short8 qf[3][2];
  #pragma unroll
  for (int hh = 0; hh < 3; hh++)
    #pragma unroll
    for (int ks = 0; ks < 2; ks++)
      qf[hh][ks] = *(const short8*)(Qg +
          (((size_t)b * NH + w * 3 + hh) * NN + n0 + lr) * ND + ks * 32 + lg * 8);

  // K B-frag prefetch registers (12 x short8 = 48 VGPR)
  short8 kreg[3][2][2];
  auto loadK = [&](int t) {
    const int m0t = t * 32;
    #pragma unroll
    for (int hh = 0; hh < 3; hh++) {
      const size_t kbase = (((size_t)b * NH + w * 3 + hh) * NN + m0t) * ND;
      #pragma unroll
      for (int j = 0; j < 2; j++)
        #pragma unroll
        for (int ks = 0; ks < 2; ks++)
          kreg[hh][j][ks] = *(const short8*)(Kg + kbase +
              (size_t)(j * 16 + lr) * ND + ks * 32 + lg * 8);
    }
  };
  // VT A-frag prefetch registers (12 x short8 = 48 VGPR), loaded in phase B(t), used in A(t+1)
  short8 vt[3][4];
  auto loadVT = [&](int t) {
    const int m0v = t * 32;
    #pragma unroll
    for (int hh = 0; hh < 3; hh++) {
      const size_t vbase = ((size_t)b * NH + w * 3 + hh) * ND * NN;
      #pragma unroll
      for (int jd = 0; jd < 4; jd++)
        vt[hh][jd] = *(const short8*)(VTg + vbase +
            (size_t)(jd * 16 + lr) * NN + m0v + lg * 8);
    }
  };

  loadK(0);
  RAWBAR();   // lwA/wwT/Sb-pad visible; loadK stays in flight
  const short8 lwf = *(const short8*)(&lwA[lr * 32 + lg * 8]);  // A[row=o][k=h]
  const short8 wwf = *(const short8*)(&wwT[lr * 32 + lg * 8]);  // B[k=o][col=o2]

  // ================= PASS 1: L[o][n] = sum_m exp(S') =================
  float Lacc[4][4];
  #pragma unroll
  for (int r = 0; r < 4; r++)
    #pragma unroll
    for (int nn = 0; nn < 4; nn++) Lacc[r][nn] = 0.f;

  for (int t = 0; t < 32; t++) {
    __builtin_amdgcn_s_setprio(1);
    #pragma unroll
    for (int hh = 0; hh < 3; hh++) {
      const int h = w * 3 + hh;
      #pragma unroll
      for (int j = 0; j < 2; j++) {
        float4v a = zf;
        #pragma unroll
        for (int ks = 0; ks < 2; ks++)
          a = __builtin_amdgcn_mfma_f32_16x16x32_bf16(qf[hh][ks], kreg[hh][j][ks], a, 0, 0, 0);
        #pragma unroll
        for (int r = 0; r < 4; r++)
          Sb[((lg * 4 + r) * 2 + j) * 576 + lr * 36 + h] = f2bf(a[r]);
      }
    }
    __builtin_amdgcn_s_setprio(0);
    loadK(t < 31 ? t + 1 : 0);   // in flight across the next two barriers
    RAWBAR();
    #pragma unroll
    for (int cc = 0; cc < 8; cc++) {
      const int c = w * 8 + cc;
      short8 sb = *(const short8*)(&Sb[c * 576 + lr * 36 + lg * 8]);
      float4v d = __builtin_amdgcn_mfma_f32_16x16x32_bf16(lwf, sb, zf, 0, 0, 0);
      #pragma unroll
      for (int r = 0; r < 4; r++)
        Lacc[r][cc >> 1] += __expf(d[r]);
    }
    RAWBAR();
  }
  float logLreg[4][4];
  #pragma unroll
  for (int r = 0; r < 4; r++)
    #pragma unroll
    for (int nn = 0; nn < 4; nn++) {
      float v = Lacc[r][nn];
      v += __shfl_xor(v, 1);
      v += __shfl_xor(v, 2);
      v += __shfl_xor(v, 4);
      v += __shfl_xor(v, 8);
      logLreg[r][nn] = __logf(v);
    }

  // ================= PASS 2: P=exp(S'-logL) -> conv_w -> PV =================
  float4v oacc[3][4];
  #pragma unroll
  for (int hh = 0; hh < 3; hh++)
    #pragma unroll
    for (int jd = 0; jd < 4; jd++) oacc[hh][jd] = zf;

  for (int t = 0; t <= 32; t++) {
    // ---- Phase A: pm reads | QK(t)->Sb | loadK(t+1) | PV(t-1) ----
    short8 pf[3];
    if (t > 0) {
      #pragma unroll
      for (int hh = 0; hh < 3; hh++)
        pf[hh] = *(const short8*)(&pm[(w * 3 + hh) * 648 + lr * 40 + lg * 8]);
    }
    __builtin_amdgcn_s_setprio(1);
    if (t < 32) {
      #pragma unroll
      for (int hh = 0; hh < 3; hh++) {
        const int h = w * 3 + hh;
        #pragma unroll
        for (int j = 0; j < 2; j++) {
          float4v a = zf;
          #pragma unroll
          for (int ks = 0; ks < 2; ks++)
            a = __builtin_amdgcn_mfma_f32_16x16x32_bf16(qf[hh][ks], kreg[hh][j][ks], a, 0, 0, 0);
          #pragma unroll
          for (int r = 0; r < 4; r++)
            Sb[((lg * 4 + r) * 2 + j) * 576 + lr * 36 + h] = f2bf(a[r]);
        }
      }
      if (t < 31) loadK(t + 1);
    }
    if (t > 0) {
      #pragma unroll
      for (int hh = 0; hh < 3; hh++)
        #pragma unroll
        for (int jd = 0; jd < 4; jd++)
          oacc[hh][jd] = __builtin_amdgcn_mfma_f32_16x16x32_bf16(vt[hh][jd], pf[hh], oacc[hh][jd], 0, 0, 0);
    }
    __builtin_amdgcn_s_setprio(0);
    RAWBAR();
    // ---- Phase B: loadVT(t) | conv_l -> exp -> conv_w -> pm ----
    if (t < 32) {
      loadVT(t);   // consumed in phase A(t+1); in flight across the barrier
      #pragma unroll
      for (int cc = 0; cc < 8; cc++) {
        const int c = w * 8 + cc;
        short8 sb = *(const short8*)(&Sb[c * 576 + lr * 36 + lg * 8]);
        float4v d = __builtin_amdgcn_mfma_f32_16x16x32_bf16(lwf, sb, zf, 0, 0, 0);
        float p0 = __expf(d[0] - logLreg[0][cc >> 1]);
        float p1 = __expf(d[1] - logLreg[1][cc >> 1]);
        float p2 = __expf(d[2] - logLreg[2][cc >> 1]);
        float p3 = __expf(d[3] - logLreg[3][cc >> 1]);
        unsigned* dst = (unsigned*)(&Sb[c * 576 + lr * 36 + lg * 4]);
        dst[0] = pk2(p0, p1);
        dst[1] = pk2(p2, p3);
      }
      asm volatile("s_waitcnt lgkmcnt(0)" ::: "memory");
      __builtin_amdgcn_sched_barrier(0);
      #pragma unroll
      for (int cc = 0; cc < 8; cc++) {
        const int c = w * 8 + cc;
        short8 pb = *(const short8*)(&Sb[c * 576 + lr * 36 + lg * 8]);
        float4v d = __builtin_amdgcn_mfma_f32_16x16x32_bf16(pb, wwf, zf, 0, 0, 0);
        unsigned* dst = (unsigned*)(&pm[lr * 648 + (c >> 1) * 40 + (c & 1) * 16 + lg * 4]);
        dst[0] = pk2(d[0], d[1]);
        dst[1] = pk2(d[2], d[3]);
      }
    }
    RAWBAR();
  }

  // epilogue: lane holds (o2, d = jd*16+lg*4.., n = n0+lr)
  #pragma unroll
  for (int hh = 0; hh < 3; hh++) {
    const int o2 = w * 3 + hh;
    #pragma unroll
    for (int jd = 0; jd < 4; jd++) {
      size_t base = ((size_t)b * NN + n0 + lr) * NC + o2 * 64 + jd * 16 + lg * 4;
      unsigned* dst = (unsigned*)(&AOut[base]);
      dst[0] = pk2(oacc[hh][jd][0], oacc[hh][jd][1]);
      dst[1] = pk2(oacc[hh][jd][2], oacc[hh][jd][3]);
    }
  }
}

extern "C" void kernel_launch(void* const* d_in, const int* in_sizes, int n_in,
                              void* d_out, int out_size, void* d_ws, size_t ws_size,
                              hipStream_t stream) {
  const float* x      = (const float*)d_in[0];
  const float* w_qkv  = (const float*)d_in[1];
  const float* w_proj = (const float*)d_in[2];
  const float* b_proj = (const float*)d_in[3];
  const float* conv_l = (const float*)d_in[4];
  const float* conv_w = (const float*)d_in[5];
  float* out = (float*)d_out;

  const size_t NE = (size_t)NB * NH * NN * ND;
  __hip_bfloat16* Qb = (__hip_bfloat16*)d_ws;
  __hip_bfloat16* Kb = Qb + NE;
  __hip_bfloat16* VT = Kb + NE;
  __hip_bfloat16* AO = VT + NE;   // [B*N][C] bf16

  gemm_kernel<0><<<dim3(18, 64), 256, 0, stream>>>(x, w_qkv, nullptr, Qb, Kb, VT, nullptr);
  attn_kernel<<<dim3(512), 256, 0, stream>>>(Qb, Kb, VT, conv_l, conv_w, AO);
  gemm_kernel<1><<<dim3(6, 64), 256, 0, stream>>>(AO, w_proj, b_proj, nullptr, nullptr, nullptr, out);
}